// Round 1
// baseline (298.546 us; speedup 1.0000x reference)
//
#include <hip/hip_runtime.h>
#include <math.h>

// Problem constants (N=512 Clements mesh, L=512 layers, fixed by reference).
#define NPORT  512
#define NLAYER 512
#define SLOTS  256                      // MZI slots per layer (4 per lane x 64 lanes)
#define ATTEN  0.9772372209558107f      // sqrt(10^(-0.2/10)) = 10^-0.01

// ---------------------------------------------------------------------------
// Kernel 1: coefficient precompute.
// For layer l, slot k (k=0..255): MZI upper port = 2k + (l&1).
// Stores {cos(th)*A, sin(th)*A, cos(ph), sin(ph)} as float4.
// Layout plane-interleaved: table[(l*4 + (k&3))*64 + (k>>2)] so that the main
// kernel's lane t reads its 4 slots (4t..4t+3) with 4 fully-coalesced
// dwordx4 loads (plane j: lane t at contiguous 16B*t).
// Invalid slot (odd layer, k=255 -> ports 511/512) gets identity coeffs
// {1,0,1,0}, which makes port 511 an exact passthrough (no attenuation),
// matching role==2 in the reference.
// ---------------------------------------------------------------------------
__global__ void coeff_kernel(const float* __restrict__ thetas,
                             const float* __restrict__ phis,
                             const int*   __restrict__ mzi_idx,
                             float4*      __restrict__ table) {
    int tid = blockIdx.x * blockDim.x + threadIdx.x;   // 0 .. NLAYER*SLOTS-1
    int l = tid >> 8;
    int k = tid & 255;
    int port_i = 2 * k + (l & 1);
    float4 c;
    if (port_i + 1 < NPORT) {
        int m = mzi_idx[l * NPORT + port_i];
        float th = thetas[m], ph = phis[m];
        c.x = cosf(th) * ATTEN;
        c.y = sinf(th) * ATTEN;
        c.z = cosf(ph);
        c.w = sinf(ph);
    } else {
        c = make_float4(1.f, 0.f, 1.f, 0.f);
    }
    table[(size_t)(l * 4 + (k & 3)) * 64 + (k >> 2)] = c;
}

// ---------------------------------------------------------------------------
// Kernel 2: mesh propagation. One wave (64 threads) per batch row.
// Lane t owns ports 8t..8t+7 in registers (complex: sr[8], si[8]).
//   Even layer: 4 lane-internal MZIs, zero communication.
//   Odd layer:  3 internal MZIs + the crossing pair (8t+7, 8t+8):
//     - fetch next lane's port0 via __shfl_down
//     - compute both outputs; keep upper, __shfl_up the lower back to lane t+1
//   Lane 63's crossing slot holds identity coeffs -> port 511 passthrough.
//   Lane 0 keeps its port 0 (passthrough) by masking the shfl_up result.
// No LDS, no __syncthreads. Coefficients double-buffered 3 layers deep so
// L2 latency (~200 cyc) is hidden behind ~300 cyc of compute.
// ---------------------------------------------------------------------------
template <bool USE_TABLE>
__global__ __launch_bounds__(64)
void mesh_kernel(const float*  __restrict__ x,
                 const float*  __restrict__ thetas,
                 const float*  __restrict__ phis,
                 const int*    __restrict__ mzi_idx,
                 const float4* __restrict__ table,
                 float*        __restrict__ out) {
    const int lane = threadIdx.x;      // 0..63
    const int row  = blockIdx.x;

    // Load 8 consecutive real inputs -> complex state (im = 0).
    const float4* xr = (const float4*)(x + (size_t)row * NPORT + lane * 8);
    float4 xa = xr[0], xb = xr[1];
    float sr[8] = {xa.x, xa.y, xa.z, xa.w, xb.x, xb.y, xb.z, xb.w};
    float si[8] = {0.f, 0.f, 0.f, 0.f, 0.f, 0.f, 0.f, 0.f};

    float4 b0[4], b1[4], b2[4], b3[4];

    auto loadL = [&](int l, float4* buf) {
        if (USE_TABLE) {
#pragma unroll
            for (int j = 0; j < 4; ++j)
                buf[j] = table[(size_t)(l * 4 + j) * 64 + lane];
        } else {
            // Fallback: compute trig inline (used only if ws is too small).
#pragma unroll
            for (int j = 0; j < 4; ++j) {
                int port_i = 8 * lane + 2 * j + (l & 1);
                if (port_i + 1 < NPORT) {
                    int m = mzi_idx[l * NPORT + port_i];
                    float th = thetas[m], ph = phis[m];
                    buf[j] = make_float4(cosf(th) * ATTEN, sinf(th) * ATTEN,
                                         cosf(ph), sinf(ph));
                } else {
                    buf[j] = make_float4(1.f, 0.f, 1.f, 0.f);
                }
            }
        }
    };

    // One MZI: ports (p0=upper, p1=lower) both lane-local.
    auto mzi = [&](const float4 c, int p0, int p1) {
        float ct = c.x, st = c.y, er = c.z, ei = c.w;
        float ur = ct * sr[p0] + st * sr[p1];
        float ui = ct * si[p0] + st * si[p1];
        float lr = ct * sr[p1] - st * sr[p0];
        float li = ct * si[p1] - st * si[p0];
        sr[p0] = er * ur - ei * ui;
        si[p0] = er * ui + ei * ur;
        sr[p1] = lr;
        si[p1] = li;
    };

    auto evenL = [&](const float4* c) {
#pragma unroll
        for (int j = 0; j < 4; ++j) mzi(c[j], 2 * j, 2 * j + 1);
    };

    auto oddL = [&](const float4* c) {
        // Neighbor's port 8(t+1) = lane t+1's local port 0.
        float nxr = __shfl_down(sr[0], 1);
        float nxi = __shfl_down(si[0], 1);
#pragma unroll
        for (int j = 0; j < 3; ++j) mzi(c[j], 2 * j + 1, 2 * j + 2);
        // Crossing MZI (local port 7, neighbor port 0).
        {
            float ct = c[3].x, st = c[3].y, er = c[3].z, ei = c[3].w;
            float ur = ct * sr[7] + st * nxr;
            float ui = ct * si[7] + st * nxi;
            float lr = ct * nxr - st * sr[7];
            float li = ct * nxi - st * si[7];
            sr[7] = er * ur - ei * ui;
            si[7] = er * ui + ei * ur;
            float rlr = __shfl_up(lr, 1);
            float rli = __shfl_up(li, 1);
            // Lanes 1..63 receive their port-0 update; lane 0's port 0 is a
            // passthrough in odd layers.
            sr[0] = (lane > 0) ? rlr : sr[0];
            si[0] = (lane > 0) ? rli : si[0];
        }
    };

    // Main loop, unrolled x4 (even/odd/even/odd), 3-layer-deep prefetch.
    loadL(0, b0);
    loadL(1, b1);
    loadL(2, b2);
    for (int l = 0; l < NLAYER; l += 4) {
        loadL(min(l + 3, NLAYER - 1), b3);
        evenL(b0);
        loadL(min(l + 4, NLAYER - 1), b0);
        oddL(b1);
        loadL(min(l + 5, NLAYER - 1), b1);
        evenL(b2);
        loadL(min(l + 6, NLAYER - 1), b2);
        oddL(b3);
    }

    // Photodetection: |E|^2, vectorized store.
    float4 o0 = make_float4(sr[0] * sr[0] + si[0] * si[0],
                            sr[1] * sr[1] + si[1] * si[1],
                            sr[2] * sr[2] + si[2] * si[2],
                            sr[3] * sr[3] + si[3] * si[3]);
    float4 o1 = make_float4(sr[4] * sr[4] + si[4] * si[4],
                            sr[5] * sr[5] + si[5] * si[5],
                            sr[6] * sr[6] + si[6] * si[6],
                            sr[7] * sr[7] + si[7] * si[7]);
    float4* op = (float4*)(out + (size_t)row * NPORT + lane * 8);
    op[0] = o0;
    op[1] = o1;
}

// ---------------------------------------------------------------------------
// Inputs (setup_inputs order): x[B*N] f32, thetas[M] f32, phis[M] f32,
// partner[L*N] i32 (unused: pairing is the fixed Clements pattern),
// mzi_idx[L*N] i32, role[L*N] i32 (unused: implied by port parity).
// ---------------------------------------------------------------------------
extern "C" void kernel_launch(void* const* d_in, const int* in_sizes, int n_in,
                              void* d_out, int out_size, void* d_ws,
                              size_t ws_size, hipStream_t stream) {
    const float* x       = (const float*)d_in[0];
    const float* thetas  = (const float*)d_in[1];
    const float* phis    = (const float*)d_in[2];
    const int*   mzi_idx = (const int*)d_in[4];
    float*       out     = (float*)d_out;

    int B = in_sizes[0] / NPORT;

    const size_t table_bytes = (size_t)NLAYER * 4 * 64 * sizeof(float4); // 2 MiB
    if (ws_size >= table_bytes) {
        float4* table = (float4*)d_ws;
        coeff_kernel<<<(NLAYER * SLOTS) / 256, 256, 0, stream>>>(
            thetas, phis, mzi_idx, table);
        mesh_kernel<true><<<B, 64, 0, stream>>>(x, thetas, phis, mzi_idx, table,
                                                out);
    } else {
        mesh_kernel<false><<<B, 64, 0, stream>>>(x, thetas, phis, mzi_idx,
                                                 nullptr, out);
    }
}